// Round 10
// baseline (1387.063 us; speedup 1.0000x reference)
//
#include <hip/hip_runtime.h>
#include <hip/hip_bf16.h>

#define DIM 128
#define G4 512      // 4*DIM
#define NL 4
#define VOCAB 32000
#define BB 32
#define SS 256
#define ROWS (BB*SS)   // 8192

typedef __attribute__((ext_vector_type(8))) short short8;
typedef __attribute__((ext_vector_type(4))) float f32x4;
typedef __attribute__((ext_vector_type(4))) unsigned int uint4v;
typedef __attribute__((ext_vector_type(2))) _Float16 h2;

__device__ __forceinline__ float fexp_(float x){ return __builtin_amdgcn_exp2f(x * 1.44269504088896f); }
__device__ __forceinline__ float frcp_(float x){ return __builtin_amdgcn_rcpf(x); }
__device__ __forceinline__ float sigm_(float x){ return frcp_(1.f + fexp_(-x)); }
__device__ __forceinline__ float tanh_(float x){
    float ax = fabsf(x);
    float e = fexp_(-2.f * ax);
    float t = (1.f - e) * frcp_(1.f + e);
    return x < 0.f ? -t : t;
}
__device__ __forceinline__ h2 mkh(float a, float b){ h2 r; r.x = (_Float16)a; r.y = (_Float16)b; return r; }

#if __has_builtin(__builtin_amdgcn_fdot2)
#define FDOT2(w, d, acc) acc = __builtin_amdgcn_fdot2(w, d, acc, false);
#else
#define FDOT2(w, d, acc) acc = fmaf((float)(w).x, (float)(d).x, fmaf((float)(w).y, (float)(d).y, acc));
#endif
#define B2H(u) __builtin_bit_cast(h2, (unsigned)(u))

// ---- 32 named half2 regs per gate (64 weights, K-chunk 64) ----
#define WD32(p) h2 p##0,p##1,p##2,p##3,p##4,p##5,p##6,p##7,p##8,p##9,p##10,p##11, \
                   p##12,p##13,p##14,p##15,p##16,p##17,p##18,p##19,p##20,p##21,p##22,p##23, \
                   p##24,p##25,p##26,p##27,p##28,p##29,p##30,p##31;
#define WCVT32(p, src) { float4 t_; \
    t_=(src)[0];  p##0 =mkh(t_.x,t_.y); p##1 =mkh(t_.z,t_.w); \
    t_=(src)[1];  p##2 =mkh(t_.x,t_.y); p##3 =mkh(t_.z,t_.w); \
    t_=(src)[2];  p##4 =mkh(t_.x,t_.y); p##5 =mkh(t_.z,t_.w); \
    t_=(src)[3];  p##6 =mkh(t_.x,t_.y); p##7 =mkh(t_.z,t_.w); \
    t_=(src)[4];  p##8 =mkh(t_.x,t_.y); p##9 =mkh(t_.z,t_.w); \
    t_=(src)[5];  p##10=mkh(t_.x,t_.y); p##11=mkh(t_.z,t_.w); \
    t_=(src)[6];  p##12=mkh(t_.x,t_.y); p##13=mkh(t_.z,t_.w); \
    t_=(src)[7];  p##14=mkh(t_.x,t_.y); p##15=mkh(t_.z,t_.w); \
    t_=(src)[8];  p##16=mkh(t_.x,t_.y); p##17=mkh(t_.z,t_.w); \
    t_=(src)[9];  p##18=mkh(t_.x,t_.y); p##19=mkh(t_.z,t_.w); \
    t_=(src)[10]; p##20=mkh(t_.x,t_.y); p##21=mkh(t_.z,t_.w); \
    t_=(src)[11]; p##22=mkh(t_.x,t_.y); p##23=mkh(t_.z,t_.w); \
    t_=(src)[12]; p##24=mkh(t_.x,t_.y); p##25=mkh(t_.z,t_.w); \
    t_=(src)[13]; p##26=mkh(t_.x,t_.y); p##27=mkh(t_.z,t_.w); \
    t_=(src)[14]; p##28=mkh(t_.x,t_.y); p##29=mkh(t_.z,t_.w); \
    t_=(src)[15]; p##30=mkh(t_.x,t_.y); p##31=mkh(t_.z,t_.w); }
#define DT_LO(p, acc) \
    FDOT2(p##0,d0,acc)  FDOT2(p##1,d1,acc)  FDOT2(p##2,d2,acc)  FDOT2(p##3,d3,acc) \
    FDOT2(p##4,d4,acc)  FDOT2(p##5,d5,acc)  FDOT2(p##6,d6,acc)  FDOT2(p##7,d7,acc) \
    FDOT2(p##8,d8,acc)  FDOT2(p##9,d9,acc)  FDOT2(p##10,d10,acc) FDOT2(p##11,d11,acc) \
    FDOT2(p##12,d12,acc) FDOT2(p##13,d13,acc) FDOT2(p##14,d14,acc) FDOT2(p##15,d15,acc)
#define DT_HI(p, acc) \
    FDOT2(p##16,d0,acc)  FDOT2(p##17,d1,acc)  FDOT2(p##18,d2,acc)  FDOT2(p##19,d3,acc) \
    FDOT2(p##20,d4,acc)  FDOT2(p##21,d5,acc)  FDOT2(p##22,d6,acc)  FDOT2(p##23,d7,acc) \
    FDOT2(p##24,d8,acc)  FDOT2(p##25,d9,acc)  FDOT2(p##26,d10,acc) FDOT2(p##27,d11,acc) \
    FDOT2(p##28,d12,acc) FDOT2(p##29,d13,acc) FDOT2(p##30,d14,acc) FDOT2(p##31,d15,acc)
#define RD16(base) { const uint4v* hc_ = (const uint4v*)(base); \
    uint4v q0_=hc_[0], q1_=hc_[1], q2_=hc_[2], q3_=hc_[3]; \
    d0=B2H(q0_.x); d1=B2H(q0_.y); d2=B2H(q0_.z); d3=B2H(q0_.w); \
    d4=B2H(q1_.x); d5=B2H(q1_.y); d6=B2H(q1_.z); d7=B2H(q1_.w); \
    d8=B2H(q2_.x); d9=B2H(q2_.y); d10=B2H(q2_.z); d11=B2H(q2_.w); \
    d12=B2H(q3_.x); d13=B2H(q3_.y); d14=B2H(q3_.z); d15=B2H(q3_.w); }

// full-K (128) fp32 macros for k_xw (1 gate/thread, broadcast h)
#define W_DECL_ALL \
    float4 w0,w1,w2,w3,w4,w5,w6,w7,w8,w9,w10,w11,w12,w13,w14,w15, \
           w16,w17,w18,w19,w20,w21,w22,w23,w24,w25,w26,w27,w28,w29,w30,w31;
#define W_LOAD(i) w##i = wr[i];
#define W_LOAD_ALL \
    W_LOAD(0) W_LOAD(1) W_LOAD(2) W_LOAD(3) W_LOAD(4) W_LOAD(5) W_LOAD(6) W_LOAD(7) \
    W_LOAD(8) W_LOAD(9) W_LOAD(10) W_LOAD(11) W_LOAD(12) W_LOAD(13) W_LOAD(14) W_LOAD(15) \
    W_LOAD(16) W_LOAD(17) W_LOAD(18) W_LOAD(19) W_LOAD(20) W_LOAD(21) W_LOAD(22) W_LOAD(23) \
    W_LOAD(24) W_LOAD(25) W_LOAD(26) W_LOAD(27) W_LOAD(28) W_LOAD(29) W_LOAD(30) W_LOAD(31)
#define FMA1(i, acc) acc = fmaf(h4[i].x, w##i.x, fmaf(h4[i].y, w##i.y, \
                      fmaf(h4[i].z, w##i.z, fmaf(h4[i].w, w##i.w, acc))));
#define DOT128(a0,a1,a2,a3) \
    FMA1(0,a0) FMA1(1,a0) FMA1(2,a0) FMA1(3,a0) FMA1(4,a0) FMA1(5,a0) FMA1(6,a0) FMA1(7,a0) \
    FMA1(8,a1) FMA1(9,a1) FMA1(10,a1) FMA1(11,a1) FMA1(12,a1) FMA1(13,a1) FMA1(14,a1) FMA1(15,a1) \
    FMA1(16,a2) FMA1(17,a2) FMA1(18,a2) FMA1(19,a2) FMA1(20,a2) FMA1(21,a2) FMA1(22,a2) FMA1(23,a2) \
    FMA1(24,a3) FMA1(25,a3) FMA1(26,a3) FMA1(27,a3) FMA1(28,a3) FMA1(29,a3) FMA1(30,a3) FMA1(31,a3)

// ---------------- K1: embedding gather ----------------
__global__ void k_embed(const int* __restrict__ x, const float* __restrict__ emb,
                        float* __restrict__ hseq){
    int i = blockIdx.x * blockDim.x + threadIdx.x;
    int row = i >> 5;
    int d4  = i & 31;
    int tok = x[row];
    ((float4*)hseq)[i] = ((const float4*)emb)[tok * 32 + d4];
}

// ---------------- K2: xw = hseq @ Wih^T + bih + bhh (cell-major layout) --------
__global__ __launch_bounds__(512, 2) void k_xw(const float* __restrict__ hseq,
                                               const float* Wih,
                                               const float* __restrict__ bih,
                                               const float* __restrict__ bhh,
                                               float* xw){
    __shared__ float hs[32 * DIM];
    int g = threadIdx.x;
    int r0 = blockIdx.x * 32;
    {
        const float4* src = (const float4*)(hseq + (size_t)r0 * DIM);
        float4* dst = (float4*)hs;
        for (int j = g; j < 32 * 32; j += 512) dst[j] = src[j];
    }
    int gg = ((g & 3) << 7) + (g >> 2);
    const float4* wr = (const float4*)(Wih + (size_t)gg * DIM);
    W_DECL_ALL
    W_LOAD_ALL
    float bias = bih[gg] + bhh[gg];
    __syncthreads();
    for (int r = 0; r < 32; ++r){
        const float4* h4 = (const float4*)(hs + r * DIM);
        float a0 = bias, a1 = 0.f, a2 = 0.f, a3 = 0.f;
        DOT128(a0, a1, a2, a3)
        xw[(size_t)(r0 + r) * G4 + g] = (a0 + a1) + (a2 + a3);
    }
}

// ---------------- K3: fused 2-layer LSTM scan (in-block pipeline) ----------------
// (unchanged from round 9 — see its header comment)
__global__ __launch_bounds__(768, 3) void k_scan2(
    const float* __restrict__ xw,
    const float* WhhA, const float* WihB, const float* WhhB,
    const float* __restrict__ bihB, const float* __restrict__ bhhB,
    float* hseqOut)
{
    __shared__ float    xwstage[2][16][512];   // 64 KB  xw_A chunks
    __shared__ float    stg[2][16][128];       // 16 KB  h_B staging
    __shared__ float4   xwbuf[2][128];         //  4 KB  B-in -> B-rec handoff
    __shared__ _Float16 hA[4][144];            // h_A ring
    __shared__ _Float16 hB[4][144];            // h_B ring

    const int tid = threadIdx.x;
    const int b = blockIdx.x;
    const int quarter = tid >> 8;        // 0=A, 1=B-rec, 2=B-in
    const int qt = tid & 255;
    const int ci = qt >> 1, kg = qt & 1;

    const float* Wsel = (quarter == 0) ? WhhA : (quarter == 1) ? WhhB : WihB;
    WD32(pi) WD32(pf) WD32(pg) WD32(po)
    {
        const float4* s0 = (const float4*)(Wsel + ((size_t)(0 * DIM + ci)) * DIM + kg * 64);
        const float4* s1 = (const float4*)(Wsel + ((size_t)(1 * DIM + ci)) * DIM + kg * 64);
        const float4* s2 = (const float4*)(Wsel + ((size_t)(2 * DIM + ci)) * DIM + kg * 64);
        const float4* s3 = (const float4*)(Wsel + ((size_t)(3 * DIM + ci)) * DIM + kg * 64);
        WCVT32(pi, s0) WCVT32(pf, s1) WCVT32(pg, s2) WCVT32(po, s3)
    }
    float4 biasv = {0.f, 0.f, 0.f, 0.f};
    if (quarter == 2){
        biasv.x = bihB[0 * DIM + ci] + bhhB[0 * DIM + ci];
        biasv.y = bihB[1 * DIM + ci] + bhhB[1 * DIM + ci];
        biasv.z = bihB[2 * DIM + ci] + bhhB[2 * DIM + ci];
        biasv.w = bihB[3 * DIM + ci] + bhhB[3 * DIM + ci];
    }
    if (tid < 576){ ((_Float16*)hA)[tid] = (_Float16)0.f; ((_Float16*)hB)[tid] = (_Float16)0.f; }
    const float4* xw4 = (const float4*)(xw + (size_t)b * SS * G4);
    {
        float4* dst = (float4*)&xwstage[0][0][0];
#pragma unroll
        for (int j = 0; j < 3; ++j){ int idx = j * 768 + tid; if (idx < 2048) dst[idx] = xw4[idx]; }
    }
    float cc = 0.f;
    float* hout = hseqOut + (size_t)b * SS * DIM;
    __syncthreads();

    for (int s = 0; s < 258; ++s){
        if (s >= 18 && ((s - 2) & 15) == 0 && tid < 512){
            int g = ((s - 2) >> 4) - 1;
            int r = tid >> 5, c4 = tid & 31;
            float4 v = *(const float4*)&stg[g & 1][r][c4 * 4];
            *(float4*)(hout + (size_t)(g * 16 + r) * DIM + c4 * 4) = v;
        }
        if ((s & 15) == 0 && s < 240){
            int c1 = (s >> 4) + 1;
            const float4* src = xw4 + c1 * 2048;
            float4* dst = (float4*)&xwstage[c1 & 1][0][0];
#pragma unroll
            for (int j = 0; j < 3; ++j){ int idx = j * 768 + tid; if (idx < 2048) dst[idx] = src[idx]; }
        }
        bool act;
        const _Float16* rb;
        if (quarter == 0){      act = (s < 256);            rb = &hA[(s - 1) & 3][kg * 64]; }
        else if (quarter == 1){ act = (s >= 2);             rb = &hB[(s - 3) & 3][kg * 64]; }
        else {                  act = (s >= 1 && s < 257);  rb = &hA[(s - 1) & 3][kg * 64]; }
        if (act){
            h2 d0,d1,d2,d3,d4,d5,d6,d7,d8,d9,d10,d11,d12,d13,d14,d15;
            float a0 = 0.f, a1 = 0.f, a2 = 0.f, a3 = 0.f;
            RD16(rb)
            DT_LO(pi, a0) DT_LO(pf, a1) DT_LO(pg, a2) DT_LO(po, a3)
            RD16(rb + 32)
            DT_HI(pi, a0) DT_HI(pf, a1) DT_HI(pg, a2) DT_HI(po, a3)
            a0 += __shfl_xor(a0, 1); a1 += __shfl_xor(a1, 1);
            a2 += __shfl_xor(a2, 1); a3 += __shfl_xor(a3, 1);
            if (quarter == 2){
                if (kg == 0){
                    float4 v; v.x = a0 + biasv.x; v.y = a1 + biasv.y;
                              v.z = a2 + biasv.z; v.w = a3 + biasv.w;
                    xwbuf[s & 1][ci] = v;
                }
            } else {
                float4 xq;
                if (quarter == 0) xq = *(const float4*)&xwstage[(s >> 4) & 1][s & 15][ci * 4];
                else              xq = xwbuf[(s - 1) & 1][ci];
                float iv = sigm_(xq.x + a0);
                float fv = sigm_(xq.y + a1);
                float gv = tanh_(xq.z + a2);
                float ov = sigm_(xq.w + a3);
                cc = fv * cc + iv * gv;
                float h = ov * tanh_(cc);
                if (quarter == 0){
                    if (kg == 0) hA[s & 3][ci] = (_Float16)h;
                } else {
                    int u = s - 2;
                    if (kg == 0) hB[u & 3][ci] = (_Float16)h;
                    else         stg[(u >> 4) & 1][u & 15][ci] = h;
                }
            }
        }
        __syncthreads();
    }
    if (tid < 512){
        int r = tid >> 5, c4 = tid & 31;
        float4 v = *(const float4*)&stg[1][r][c4 * 4];
        *(float4*)(hout + (size_t)(240 + r) * DIM + c4 * 4) = v;
    }
}

// ---------------- K4: LayerNorm -> bf16 ----------------
__global__ void k_ln(const float* __restrict__ hseq, const float* __restrict__ gamma,
                     const float* __restrict__ beta, __hip_bfloat16* __restrict__ hn){
    int wid = threadIdx.x >> 6;
    int lane = threadIdx.x & 63;
    int row = blockIdx.x * 4 + wid;
    float2 hv = ((const float2*)(hseq + (size_t)row * DIM))[lane];
    float s = hv.x + hv.y;
    float sq = fmaf(hv.x, hv.x, hv.y * hv.y);
    for (int off = 32; off; off >>= 1){ s += __shfl_xor(s, off); sq += __shfl_xor(sq, off); }
    float mu = s * (1.f / 128.f);
    float var = sq * (1.f / 128.f) - mu * mu;
    float inv = rsqrtf(var + 1e-5f);
    float2 gv = ((const float2*)gamma)[lane];
    float2 bv = ((const float2*)beta)[lane];
    __hip_bfloat162 pr;
    pr.x = __float2bfloat16((hv.x - mu) * inv * gv.x + bv.x);
    pr.y = __float2bfloat16((hv.y - mu) * inv * gv.y + bv.y);
    ((__hip_bfloat162*)hn)[(size_t)row * 64 + lane] = pr;
}

// ---------------- K5: head_W fp32 -> bf16 ----------------
__global__ void k_cvt(const float* __restrict__ w, __hip_bfloat16* __restrict__ wb){
    int i = blockIdx.x * blockDim.x + threadIdx.x;
    float4 v = ((const float4*)w)[i];
    __hip_bfloat162 p0, p1;
    p0.x = __float2bfloat16(v.x); p0.y = __float2bfloat16(v.y);
    p1.x = __float2bfloat16(v.z); p1.y = __float2bfloat16(v.w);
    ((__hip_bfloat162*)wb)[2 * i]     = p0;
    ((__hip_bfloat162*)wb)[2 * i + 1] = p1;
}

// ---------------- K6: head GEMM — 64x256 tile, plain float4 stores ----------------
// ROUND-10 CHANGE (isolated): tile 128x128 -> 64x256 (1 KB contiguous per row
// per block, 4x longer write runs) and nontemporal -> plain stores (restore L2
// write-combining; NT may have been splitting 128B lines into 64B HBM partials).
// 4 waves each own a 64x64 quadrant: col0 = bn*256 + wid*64, rows shared.
__global__ __launch_bounds__(256) void k_head(const __hip_bfloat16* __restrict__ hn,
                                              const __hip_bfloat16* __restrict__ wb,
                                              const float* __restrict__ head_b,
                                              float* __restrict__ out){
    int bn = blockIdx.x;          // 125 col tiles of 256
    int bm = blockIdx.y;          // 128 row tiles of 64
    int wid = threadIdx.x >> 6;
    int lane = threadIdx.x & 63;
    int row0 = bm * 64;
    int col0 = bn * 256 + wid * 64;
    const short* A  = (const short*)hn;   // [8192][128]
    const short* Bp = (const short*)wb;   // [32000][128]
    f32x4 zero = {0.f, 0.f, 0.f, 0.f};
    f32x4 acc[4][4];   // [mi][ni]
#pragma unroll
    for (int i = 0; i < 4; ++i)
#pragma unroll
        for (int j = 0; j < 4; ++j) acc[i][j] = zero;
    int lrow = lane & 15;
    int kgr = (lane >> 4) * 8;
#pragma unroll
    for (int ks = 0; ks < 4; ++ks){
        short8 a[4], bf[4];
#pragma unroll
        for (int mi = 0; mi < 4; ++mi)
            a[mi] = *(const short8*)(A + (size_t)(row0 + mi * 16 + lrow) * DIM + ks * 32 + kgr);
#pragma unroll
        for (int ni = 0; ni < 4; ++ni)
            bf[ni] = *(const short8*)(Bp + (size_t)(col0 + ni * 16 + lrow) * DIM + ks * 32 + kgr);
#pragma unroll
        for (int mi = 0; mi < 4; ++mi)
#pragma unroll
            for (int ni = 0; ni < 4; ++ni)
                acc[mi][ni] = __builtin_amdgcn_mfma_f32_16x16x32_bf16(bf[ni], a[mi], acc[mi][ni], 0, 0, 0);
    }
    int csub = (lane >> 4) * 4;
#pragma unroll
    for (int ni = 0; ni < 4; ++ni){
        int cbase = col0 + ni * 16 + csub;
        float4 b4 = ((const float4*)head_b)[cbase >> 2];
#pragma unroll
        for (int mi = 0; mi < 4; ++mi){
            int row = row0 + mi * 16 + lrow;
            float4 v;
            v.x = acc[mi][ni][0] + b4.x;
            v.y = acc[mi][ni][1] + b4.y;
            v.z = acc[mi][ni][2] + b4.z;
            v.w = acc[mi][ni][3] + b4.w;
            *(float4*)(out + (size_t)row * VOCAB + cbase) = v;
        }
    }
}

extern "C" void kernel_launch(void* const* d_in, const int* in_sizes, int n_in,
                              void* d_out, int out_size, void* d_ws, size_t ws_size,
                              hipStream_t stream){
    const int*   x     = (const int*)  d_in[0];
    const float* emb   = (const float*)d_in[1];
    const float* Wih   = (const float*)d_in[2];
    const float* Whh   = (const float*)d_in[3];
    const float* bih   = (const float*)d_in[4];
    const float* bhh   = (const float*)d_in[5];
    const float* gamma = (const float*)d_in[6];
    const float* beta  = (const float*)d_in[7];
    const float* headW = (const float*)d_in[8];
    const float* headb = (const float*)d_in[9];
    float* out = (float*)d_out;

    char* ws = (char*)d_ws;
    float* xw   = (float*)ws;                                  // 16 MB [8192][512] (cell-major)
    float* hseq = (float*)(ws + (16u << 20));                  // 4 MB  [8192][128]
    __hip_bfloat16* hn = (__hip_bfloat16*)(ws + (20u << 20));  // 2 MB
    __hip_bfloat16* wb = (__hip_bfloat16*)(ws + (22u << 20));  // 8 MB

    const size_t WSZ = (size_t)G4 * DIM;

    k_embed<<<1024, 256, 0, stream>>>(x, emb, hseq);
    k_cvt  <<<4000, 256, 0, stream>>>(headW, wb);
    k_xw   <<<256, 512, 0, stream>>>(hseq, Wih, bih, bhh, xw);
    k_scan2<<<32, 768, 0, stream>>>(xw, Whh, Wih + WSZ, Whh + WSZ,
                                    bih + G4, bhh + G4, hseq);
    k_xw   <<<256, 512, 0, stream>>>(hseq, Wih + 2 * WSZ, bih + 2 * G4, bhh + 2 * G4, xw);
    k_scan2<<<32, 768, 0, stream>>>(xw, Whh + 2 * WSZ, Wih + 3 * WSZ, Whh + 3 * WSZ,
                                    bih + 3 * G4, bhh + 3 * G4, hseq);
    k_ln   <<<2048, 256, 0, stream>>>(hseq, gamma, beta, hn);
    k_head <<<dim3(125, 128), 256, 0, stream>>>(hn, wb, headb, out);
}

// Round 11
// 1254.495 us; speedup vs baseline: 1.1057x; 1.1057x over previous
//
#include <hip/hip_runtime.h>
#include <hip/hip_bf16.h>

#define DIM 128
#define G4 512      // 4*DIM
#define NL 4
#define VOCAB 32000
#define BB 32
#define SS 256
#define ROWS (BB*SS)   // 8192

typedef __attribute__((ext_vector_type(8))) short short8;
typedef __attribute__((ext_vector_type(4))) float f32x4;
typedef __attribute__((ext_vector_type(4))) unsigned int uint4v;
typedef __attribute__((ext_vector_type(2))) _Float16 h2;

__device__ __forceinline__ float fexp_(float x){ return __builtin_amdgcn_exp2f(x * 1.44269504088896f); }
__device__ __forceinline__ float frcp_(float x){ return __builtin_amdgcn_rcpf(x); }
__device__ __forceinline__ float sigm_(float x){ return frcp_(1.f + fexp_(-x)); }
__device__ __forceinline__ float tanh_(float x){
    float ax = fabsf(x);
    float e = fexp_(-2.f * ax);
    float t = (1.f - e) * frcp_(1.f + e);
    return x < 0.f ? -t : t;
}
__device__ __forceinline__ h2 mkh(float a, float b){ h2 r; r.x = (_Float16)a; r.y = (_Float16)b; return r; }

#if __has_builtin(__builtin_amdgcn_fdot2)
#define FDOT2(w, d, acc) acc = __builtin_amdgcn_fdot2(w, d, acc, false);
#else
#define FDOT2(w, d, acc) acc = fmaf((float)(w).x, (float)(d).x, fmaf((float)(w).y, (float)(d).y, acc));
#endif
#define B2H(u) __builtin_bit_cast(h2, (unsigned)(u))

// ---- 32 named half2 regs (64 f16 weights = one K-half of one gate row) ----
#define WD32(p) h2 p##0,p##1,p##2,p##3,p##4,p##5,p##6,p##7,p##8,p##9,p##10,p##11, \
                   p##12,p##13,p##14,p##15,p##16,p##17,p##18,p##19,p##20,p##21,p##22,p##23, \
                   p##24,p##25,p##26,p##27,p##28,p##29,p##30,p##31;
#define WCVT32(p, src) { float4 t_; \
    t_=(src)[0];  p##0 =mkh(t_.x,t_.y); p##1 =mkh(t_.z,t_.w); \
    t_=(src)[1];  p##2 =mkh(t_.x,t_.y); p##3 =mkh(t_.z,t_.w); \
    t_=(src)[2];  p##4 =mkh(t_.x,t_.y); p##5 =mkh(t_.z,t_.w); \
    t_=(src)[3];  p##6 =mkh(t_.x,t_.y); p##7 =mkh(t_.z,t_.w); \
    t_=(src)[4];  p##8 =mkh(t_.x,t_.y); p##9 =mkh(t_.z,t_.w); \
    t_=(src)[5];  p##10=mkh(t_.x,t_.y); p##11=mkh(t_.z,t_.w); \
    t_=(src)[6];  p##12=mkh(t_.x,t_.y); p##13=mkh(t_.z,t_.w); \
    t_=(src)[7];  p##14=mkh(t_.x,t_.y); p##15=mkh(t_.z,t_.w); \
    t_=(src)[8];  p##16=mkh(t_.x,t_.y); p##17=mkh(t_.z,t_.w); \
    t_=(src)[9];  p##18=mkh(t_.x,t_.y); p##19=mkh(t_.z,t_.w); \
    t_=(src)[10]; p##20=mkh(t_.x,t_.y); p##21=mkh(t_.z,t_.w); \
    t_=(src)[11]; p##22=mkh(t_.x,t_.y); p##23=mkh(t_.z,t_.w); \
    t_=(src)[12]; p##24=mkh(t_.x,t_.y); p##25=mkh(t_.z,t_.w); \
    t_=(src)[13]; p##26=mkh(t_.x,t_.y); p##27=mkh(t_.z,t_.w); \
    t_=(src)[14]; p##28=mkh(t_.x,t_.y); p##29=mkh(t_.z,t_.w); \
    t_=(src)[15]; p##30=mkh(t_.x,t_.y); p##31=mkh(t_.z,t_.w); }
// dot of 32 weight-h2 against data d0..d31
#define DT32(p, acc) \
    FDOT2(p##0,d0,acc)  FDOT2(p##1,d1,acc)  FDOT2(p##2,d2,acc)  FDOT2(p##3,d3,acc) \
    FDOT2(p##4,d4,acc)  FDOT2(p##5,d5,acc)  FDOT2(p##6,d6,acc)  FDOT2(p##7,d7,acc) \
    FDOT2(p##8,d8,acc)  FDOT2(p##9,d9,acc)  FDOT2(p##10,d10,acc) FDOT2(p##11,d11,acc) \
    FDOT2(p##12,d12,acc) FDOT2(p##13,d13,acc) FDOT2(p##14,d14,acc) FDOT2(p##15,d15,acc) \
    FDOT2(p##16,d16,acc) FDOT2(p##17,d17,acc) FDOT2(p##18,d18,acc) FDOT2(p##19,d19,acc) \
    FDOT2(p##20,d20,acc) FDOT2(p##21,d21,acc) FDOT2(p##22,d22,acc) FDOT2(p##23,d23,acc) \
    FDOT2(p##24,d24,acc) FDOT2(p##25,d25,acc) FDOT2(p##26,d26,acc) FDOT2(p##27,d27,acc) \
    FDOT2(p##28,d28,acc) FDOT2(p##29,d29,acc) FDOT2(p##30,d30,acc) FDOT2(p##31,d31,acc)
// 64 f16 (128B) from LDS, uniform address -> broadcast, 8x ds_read_b128
#define RD32(base) { const uint4v* hc_ = (const uint4v*)(base); \
    uint4v q0_=hc_[0], q1_=hc_[1], q2_=hc_[2], q3_=hc_[3], \
           q4_=hc_[4], q5_=hc_[5], q6_=hc_[6], q7_=hc_[7]; \
    d0=B2H(q0_.x); d1=B2H(q0_.y); d2=B2H(q0_.z); d3=B2H(q0_.w); \
    d4=B2H(q1_.x); d5=B2H(q1_.y); d6=B2H(q1_.z); d7=B2H(q1_.w); \
    d8=B2H(q2_.x); d9=B2H(q2_.y); d10=B2H(q2_.z); d11=B2H(q2_.w); \
    d12=B2H(q3_.x); d13=B2H(q3_.y); d14=B2H(q3_.z); d15=B2H(q3_.w); \
    d16=B2H(q4_.x); d17=B2H(q4_.y); d18=B2H(q4_.z); d19=B2H(q4_.w); \
    d20=B2H(q5_.x); d21=B2H(q5_.y); d22=B2H(q5_.z); d23=B2H(q5_.w); \
    d24=B2H(q6_.x); d25=B2H(q6_.y); d26=B2H(q6_.z); d27=B2H(q6_.w); \
    d28=B2H(q7_.x); d29=B2H(q7_.y); d30=B2H(q7_.z); d31=B2H(q7_.w); }

// full-K (128) fp32 macros for k_xw (1 gate/thread, broadcast h)
#define W_DECL_ALL \
    float4 w0,w1,w2,w3,w4,w5,w6,w7,w8,w9,w10,w11,w12,w13,w14,w15, \
           w16,w17,w18,w19,w20,w21,w22,w23,w24,w25,w26,w27,w28,w29,w30,w31;
#define W_LOAD(i) w##i = wr[i];
#define W_LOAD_ALL \
    W_LOAD(0) W_LOAD(1) W_LOAD(2) W_LOAD(3) W_LOAD(4) W_LOAD(5) W_LOAD(6) W_LOAD(7) \
    W_LOAD(8) W_LOAD(9) W_LOAD(10) W_LOAD(11) W_LOAD(12) W_LOAD(13) W_LOAD(14) W_LOAD(15) \
    W_LOAD(16) W_LOAD(17) W_LOAD(18) W_LOAD(19) W_LOAD(20) W_LOAD(21) W_LOAD(22) W_LOAD(23) \
    W_LOAD(24) W_LOAD(25) W_LOAD(26) W_LOAD(27) W_LOAD(28) W_LOAD(29) W_LOAD(30) W_LOAD(31)
#define FMA1(i, acc) acc = fmaf(h4[i].x, w##i.x, fmaf(h4[i].y, w##i.y, \
                      fmaf(h4[i].z, w##i.z, fmaf(h4[i].w, w##i.w, acc))));
#define DOT128(a0,a1,a2,a3) \
    FMA1(0,a0) FMA1(1,a0) FMA1(2,a0) FMA1(3,a0) FMA1(4,a0) FMA1(5,a0) FMA1(6,a0) FMA1(7,a0) \
    FMA1(8,a1) FMA1(9,a1) FMA1(10,a1) FMA1(11,a1) FMA1(12,a1) FMA1(13,a1) FMA1(14,a1) FMA1(15,a1) \
    FMA1(16,a2) FMA1(17,a2) FMA1(18,a2) FMA1(19,a2) FMA1(20,a2) FMA1(21,a2) FMA1(22,a2) FMA1(23,a2) \
    FMA1(24,a3) FMA1(25,a3) FMA1(26,a3) FMA1(27,a3) FMA1(28,a3) FMA1(29,a3) FMA1(30,a3) FMA1(31,a3)

// ---------------- K1: embedding gather ----------------
__global__ void k_embed(const int* __restrict__ x, const float* __restrict__ emb,
                        float* __restrict__ hseq){
    int i = blockIdx.x * blockDim.x + threadIdx.x;
    int row = i >> 5;
    int d4  = i & 31;
    int tok = x[row];
    ((float4*)hseq)[i] = ((const float4*)emb)[tok * 32 + d4];
}

// ---------------- K2: xw = hseq @ Wih^T + bih + bhh (cell-major layout) --------
__global__ __launch_bounds__(512, 2) void k_xw(const float* __restrict__ hseq,
                                               const float* Wih,
                                               const float* __restrict__ bih,
                                               const float* __restrict__ bhh,
                                               float* xw){
    __shared__ float hs[32 * DIM];
    int g = threadIdx.x;
    int r0 = blockIdx.x * 32;
    {
        const float4* src = (const float4*)(hseq + (size_t)r0 * DIM);
        float4* dst = (float4*)hs;
        for (int j = g; j < 32 * 32; j += 512) dst[j] = src[j];
    }
    int gg = ((g & 3) << 7) + (g >> 2);
    const float4* wr = (const float4*)(Wih + (size_t)gg * DIM);
    W_DECL_ALL
    W_LOAD_ALL
    float bias = bih[gg] + bhh[gg];
    __syncthreads();
    for (int r = 0; r < 32; ++r){
        const float4* h4 = (const float4*)(hs + r * DIM);
        float a0 = bias, a1 = 0.f, a2 = 0.f, a3 = 0.f;
        DOT128(a0, a1, a2, a3)
        xw[(size_t)(r0 + r) * G4 + g] = (a0 + a1) + (a2 + a3);
    }
}

// ---------------- K3: LSTM scan — fat threads, 4 waves, pair-exchange ----------
// 32 blocks (one per batch) x 256 threads. Thread t = (ci=t>>1, w=t&1) owns gate
// rows {2w, 2w+1} of cell ci at FULL K=128 -> 128 named h2 VGPRs (launch_bounds
// (256,1) -> 512-VGPR budget, no spill). Per step: 128 fdot2, h via uniform-
// address LDS broadcast (conflict-free), xw added pre-exchange, ONE shfl_xor(1)
// pair exchange gives both threads all 4 gate sums -> redundant cell update.
// Single barrier over only 4 waves. xw register-chunked 16 steps (R8); h flushed
// to global once per chunk. Whh/hseq non-restrict (no weight remat).
__global__ __launch_bounds__(256, 1) void k_scan(const float* __restrict__ xw,
                                                 const float* Whh,
                                                 float* hseq){
    __shared__ _Float16 hb[2][DIM];       // h ring (f16), uniform-read
    __shared__ float    stg[2][16][DIM];  // h staging for global flush
    const int tid = threadIdx.x;
    const int b = blockIdx.x;
    const int ci = tid >> 1;     // cell 0..127
    const int w  = tid & 1;      // gate-half: 0 -> {i,f}, 1 -> {g,o}

    WD32(pA) WD32(pB) WD32(pC) WD32(pD)   // gate 2w: A(K0-63)+B(K64-127); gate 2w+1: C+D
    {
        const float4* r0 = (const float4*)(Whh + (size_t)((2 * w    ) * DIM + ci) * DIM);
        const float4* r1 = (const float4*)(Whh + (size_t)((2 * w + 1) * DIM + ci) * DIM);
        WCVT32(pA, r0) WCVT32(pB, r0 + 16)
        WCVT32(pC, r1) WCVT32(pD, r1 + 16)
    }
    float cc = 0.f;
    if (tid < DIM) hb[0][tid] = (_Float16)0.f;
    const float2* xw2 = (const float2*)(xw + (size_t)b * SS * G4);   // [256][256] float2
    float* hout = hseq + (size_t)b * SS * DIM;
    __syncthreads();
    int p = 0;

#define SCAN_STEP(XC, CH, I) { \
        h2 d0,d1,d2,d3,d4,d5,d6,d7,d8,d9,d10,d11,d12,d13,d14,d15, \
           d16,d17,d18,d19,d20,d21,d22,d23,d24,d25,d26,d27,d28,d29,d30,d31; \
        float s0 = XC.x, s1 = XC.y; \
        RD32(&hb[p][0]) \
        DT32(pA, s0) DT32(pC, s1) \
        RD32(&hb[p][64]) \
        DT32(pB, s0) DT32(pD, s1) \
        float o0 = __shfl_xor(s0, 1), o1 = __shfl_xor(s1, 1); \
        float i_pre = w ? o0 : s0, f_pre = w ? o1 : s1; \
        float g_pre = w ? s0 : o0, o_pre = w ? s1 : o1; \
        float iv = sigm_(i_pre), fv = sigm_(f_pre); \
        float gv = tanh_(g_pre), ov = sigm_(o_pre); \
        cc = fv * cc + iv * gv; \
        float h = ov * tanh_(cc); \
        if (!w) hb[p ^ 1][ci] = (_Float16)h; \
        else    stg[(CH) & 1][I][ci] = h; \
        __syncthreads(); \
        p ^= 1; }

    for (int ch = 0; ch < 16; ++ch){
        if (ch > 0){   // flush previous chunk's 16x128 h tile (drains at next barrier)
#pragma unroll
            for (int j = 0; j < 2; ++j){
                int idx = j * 256 + tid;
                int r = idx >> 5, c4 = idx & 31;
                float4 v = *(const float4*)&stg[(ch - 1) & 1][r][c4 * 4];
                *(float4*)(hout + (size_t)((ch - 1) * 16 + r) * DIM + c4 * 4) = v;
            }
        }
        const int t0 = ch * 16;
        float2 xc0  = xw2[(t0 +  0) * 256 + tid], xc1  = xw2[(t0 +  1) * 256 + tid],
               xc2  = xw2[(t0 +  2) * 256 + tid], xc3  = xw2[(t0 +  3) * 256 + tid],
               xc4  = xw2[(t0 +  4) * 256 + tid], xc5  = xw2[(t0 +  5) * 256 + tid],
               xc6  = xw2[(t0 +  6) * 256 + tid], xc7  = xw2[(t0 +  7) * 256 + tid],
               xc8  = xw2[(t0 +  8) * 256 + tid], xc9  = xw2[(t0 +  9) * 256 + tid],
               xc10 = xw2[(t0 + 10) * 256 + tid], xc11 = xw2[(t0 + 11) * 256 + tid],
               xc12 = xw2[(t0 + 12) * 256 + tid], xc13 = xw2[(t0 + 13) * 256 + tid],
               xc14 = xw2[(t0 + 14) * 256 + tid], xc15 = xw2[(t0 + 15) * 256 + tid];
        SCAN_STEP(xc0,  ch, 0)  SCAN_STEP(xc1,  ch, 1)  SCAN_STEP(xc2,  ch, 2)  SCAN_STEP(xc3,  ch, 3)
        SCAN_STEP(xc4,  ch, 4)  SCAN_STEP(xc5,  ch, 5)  SCAN_STEP(xc6,  ch, 6)  SCAN_STEP(xc7,  ch, 7)
        SCAN_STEP(xc8,  ch, 8)  SCAN_STEP(xc9,  ch, 9)  SCAN_STEP(xc10, ch, 10) SCAN_STEP(xc11, ch, 11)
        SCAN_STEP(xc12, ch, 12) SCAN_STEP(xc13, ch, 13) SCAN_STEP(xc14, ch, 14) SCAN_STEP(xc15, ch, 15)
    }
    {   // final flush (chunk 15 -> stg buffer 1)
#pragma unroll
        for (int j = 0; j < 2; ++j){
            int idx = j * 256 + tid;
            int r = idx >> 5, c4 = idx & 31;
            float4 v = *(const float4*)&stg[1][r][c4 * 4];
            *(float4*)(hout + (size_t)(240 + r) * DIM + c4 * 4) = v;
        }
    }
#undef SCAN_STEP
}

// ---------------- K4: LayerNorm -> bf16 ----------------
__global__ void k_ln(const float* __restrict__ hseq, const float* __restrict__ gamma,
                     const float* __restrict__ beta, __hip_bfloat16* __restrict__ hn){
    int wid = threadIdx.x >> 6;
    int lane = threadIdx.x & 63;
    int row = blockIdx.x * 4 + wid;
    float2 hv = ((const float2*)(hseq + (size_t)row * DIM))[lane];
    float s = hv.x + hv.y;
    float sq = fmaf(hv.x, hv.x, hv.y * hv.y);
    for (int off = 32; off; off >>= 1){ s += __shfl_xor(s, off); sq += __shfl_xor(sq, off); }
    float mu = s * (1.f / 128.f);
    float var = sq * (1.f / 128.f) - mu * mu;
    float inv = rsqrtf(var + 1e-5f);
    float2 gv = ((const float2*)gamma)[lane];
    float2 bv = ((const float2*)beta)[lane];
    __hip_bfloat162 pr;
    pr.x = __float2bfloat16((hv.x - mu) * inv * gv.x + bv.x);
    pr.y = __float2bfloat16((hv.y - mu) * inv * gv.y + bv.y);
    ((__hip_bfloat162*)hn)[(size_t)row * 64 + lane] = pr;
}

// ---------------- K5: head_W fp32 -> bf16 ----------------
__global__ void k_cvt(const float* __restrict__ w, __hip_bfloat16* __restrict__ wb){
    int i = blockIdx.x * blockDim.x + threadIdx.x;
    float4 v = ((const float4*)w)[i];
    __hip_bfloat162 p0, p1;
    p0.x = __float2bfloat16(v.x); p0.y = __float2bfloat16(v.y);
    p1.x = __float2bfloat16(v.z); p1.y = __float2bfloat16(v.w);
    ((__hip_bfloat162*)wb)[2 * i]     = p0;
    ((__hip_bfloat162*)wb)[2 * i + 1] = p1;
}

// ---------------- K6: head GEMM — REVERTED to round-9 config ----------------
// 128x128 tile + NONTEMPORAL stores (round-10 A/B: plain stores + 64x256 tile
// cost +122 us; NT keeps the 1 GB write stream out of L2, preserving B-panels).
__global__ __launch_bounds__(256) void k_head(const __hip_bfloat16* __restrict__ hn,
                                              const __hip_bfloat16* __restrict__ wb,
                                              const float* __restrict__ head_b,
                                              float* __restrict__ out){
    int bn = blockIdx.x;
    int bm = blockIdx.y;
    int wid = threadIdx.x >> 6;
    int lane = threadIdx.x & 63;
    int wr = wid >> 1, wc = wid & 1;
    int row0 = bm * 128 + wr * 64;
    int col0 = bn * 128 + wc * 64;
    const short* A  = (const short*)hn;   // [8192][128]
    const short* Bp = (const short*)wb;   // [32000][128]
    f32x4 zero = {0.f, 0.f, 0.f, 0.f};
    f32x4 acc[4][4];
#pragma unroll
    for (int i = 0; i < 4; ++i)
#pragma unroll
        for (int j = 0; j < 4; ++j) acc[i][j] = zero;
    int lrow = lane & 15;
    int kgr = (lane >> 4) * 8;
#pragma unroll
    for (int ks = 0; ks < 4; ++ks){
        short8 a[4], bf[4];
#pragma unroll
        for (int mi = 0; mi < 4; ++mi)
            a[mi] = *(const short8*)(A + (size_t)(row0 + mi * 16 + lrow) * DIM + ks * 32 + kgr);
#pragma unroll
        for (int ni = 0; ni < 4; ++ni)
            bf[ni] = *(const short8*)(Bp + (size_t)(col0 + ni * 16 + lrow) * DIM + ks * 32 + kgr);
#pragma unroll
        for (int mi = 0; mi < 4; ++mi)
#pragma unroll
            for (int ni = 0; ni < 4; ++ni)
                acc[mi][ni] = __builtin_amdgcn_mfma_f32_16x16x32_bf16(bf[ni], a[mi], acc[mi][ni], 0, 0, 0);
    }
    int csub = (lane >> 4) * 4;
#pragma unroll
    for (int ni = 0; ni < 4; ++ni){
        int cbase = col0 + ni * 16 + csub;
        float4 b4 = ((const float4*)head_b)[cbase >> 2];
#pragma unroll
        for (int mi = 0; mi < 4; ++mi){
            int row = row0 + mi * 16 + lrow;
            f32x4 v;
            v[0] = acc[mi][ni][0] + b4.x;
            v[1] = acc[mi][ni][1] + b4.y;
            v[2] = acc[mi][ni][2] + b4.z;
            v[3] = acc[mi][ni][3] + b4.w;
            __builtin_nontemporal_store(v, (f32x4*)(out + (size_t)row * VOCAB + cbase));
        }
    }
}

extern "C" void kernel_launch(void* const* d_in, const int* in_sizes, int n_in,
                              void* d_out, int out_size, void* d_ws, size_t ws_size,
                              hipStream_t stream){
    const int*   x     = (const int*)  d_in[0];
    const float* emb   = (const float*)d_in[1];
    const float* Wih   = (const float*)d_in[2];
    const float* Whh   = (const float*)d_in[3];
    const float* bih   = (const float*)d_in[4];
    const float* bhh   = (const float*)d_in[5];
    const float* gamma = (const float*)d_in[6];
    const float* beta  = (const float*)d_in[7];
    const float* headW = (const float*)d_in[8];
    const float* headb = (const float*)d_in[9];
    float* out = (float*)d_out;

    char* ws = (char*)d_ws;
    float* xw   = (float*)ws;                                  // 16 MB [8192][512] (cell-major)
    float* hseq = (float*)(ws + (16u << 20));                  // 4 MB  [8192][128]
    __hip_bfloat16* hn = (__hip_bfloat16*)(ws + (20u << 20));  // 2 MB
    __hip_bfloat16* wb = (__hip_bfloat16*)(ws + (22u << 20));  // 8 MB

    const size_t WSZ = (size_t)G4 * DIM;

    k_embed<<<1024, 256, 0, stream>>>(x, emb, hseq);
    k_cvt  <<<4000, 256, 0, stream>>>(headW, wb);
    for (int l = 0; l < NL; ++l){
        k_xw  <<<256, 512, 0, stream>>>(hseq, Wih + (size_t)l * WSZ,
                                        bih + l * G4, bhh + l * G4, xw);
        k_scan<<<32, 256, 0, stream>>>(xw, Whh + (size_t)l * WSZ, hseq);
    }
    k_ln   <<<2048, 256, 0, stream>>>(hseq, gamma, beta, hn);
    k_head <<<dim3(250, 64), 256, 0, stream>>>(hn, wb, headb, out);
}